// Round 2
// baseline (1130.520 us; speedup 1.0000x reference)
//
#include <hip/hip_runtime.h>
#include <stdint.h>

// CascadeAttention decode, MI355X (gfx950).
//   q [32, 4096], kv_cache [3328, 2, 16, 8, 128], page idx arrays int32,
//   out [32, 4096]. Element dtype (fp32 vs bf16) is DETECTED at runtime from
//   q's bit patterns (see detect in kernel) because the harness's actual
//   storage dtype could not be established from two failing rounds; the
//   attention body is templated on element type, both instantiations compiled.
//
// One block per (b, kv_head) = 256 blocks; bid%8 = kvh so blocks sharing a
// kvh's shared-prefix KV land on one XCD (round-robin dispatch) for L2 reuse.
// 512 threads = 8 waves; each wave online-softmaxes 44 pages (704 tokens);
// wave states merged via LDS with an exact LSE-weighted merge.

namespace {
constexpr int kG = 4;           // GQA group size (32 q heads / 8 kv heads)
constexpr int kD = 128;
constexpr int kL0P = 256, kL1P = 64, kL2P = 32;
constexpr int kTotP = kL0P + kL1P + kL2P;   // 352 pages per (b, kvh)
constexpr int kWaves = 8;
constexpr int kPPW = kTotP / kWaves;        // 44 pages per wave
constexpr int kTiles = kPPW / 4;            // 11 tiles of 4 pages (64 tokens)
constexpr float kScale = 0.08838834764831845f;
constexpr float kLog2e = 1.4426950408889634f;
// kv_cache strides in ELEMENTS: page = 2*16*8*128 = 32768, K->V = 16384,
// token = 8*128 = 1024, kvh = 128.
}

// ---- dtype-polymorphic element access -------------------------------------
__device__ __forceinline__ float ld1(const float* p) { return *p; }
__device__ __forceinline__ float ld1(const unsigned short* p) {
    return __uint_as_float(((unsigned)*p) << 16);
}
__device__ __forceinline__ void load8(const float* p, float* f) {
    float4 a = *(const float4*)p;
    float4 b = *((const float4*)p + 1);
    f[0] = a.x; f[1] = a.y; f[2] = a.z; f[3] = a.w;
    f[4] = b.x; f[5] = b.y; f[6] = b.z; f[7] = b.w;
}
__device__ __forceinline__ void load8(const unsigned short* p, float* f) {
    uint4 r = *(const uint4*)p;
    f[0] = __uint_as_float(r.x << 16); f[1] = __uint_as_float(r.x & 0xffff0000u);
    f[2] = __uint_as_float(r.y << 16); f[3] = __uint_as_float(r.y & 0xffff0000u);
    f[4] = __uint_as_float(r.z << 16); f[5] = __uint_as_float(r.z & 0xffff0000u);
    f[6] = __uint_as_float(r.w << 16); f[7] = __uint_as_float(r.w & 0xffff0000u);
}
__device__ __forceinline__ void st1(float* p, float v) { *p = v; }
__device__ __forceinline__ void st1(unsigned short* p, float v) {
    unsigned u = __float_as_uint(v);
    *p = (unsigned short)((u + 0x7fffu + ((u >> 16) & 1u)) >> 16);  // RNE
}

__device__ __forceinline__ float wave_max(float v) {
#pragma unroll
    for (int off = 1; off < 64; off <<= 1) v = fmaxf(v, __shfl_xor(v, off));
    return v;
}
__device__ __forceinline__ float wave_sum(float v) {
#pragma unroll
    for (int off = 1; off < 64; off <<= 1) v += __shfl_xor(v, off);
    return v;
}

// ---- the attention body, templated on storage element type ----------------
template <typename T>
__device__ void run_attn(const T* __restrict__ q, const T* __restrict__ kv,
                         const int* __restrict__ sp0, const int* __restrict__ sp1,
                         const int* __restrict__ sp2, T* __restrict__ out,
                         int b, int h, int tid)
{
    __shared__ __align__(16) float qs[kG * kD];   // q pre-scaled by SCALE*log2e
    __shared__ int plist[kTotP];
    __shared__ __align__(16) float wacc[kWaves][kG * kD];
    __shared__ float wm[kWaves][kG];
    __shared__ float wl[kWaves][kG];

    // --- prep: q into LDS (fp32, pre-scaled), page list into LDS ---
    {
        const int g = tid >> 7;
        const int d = tid & 127;
        float qv = ld1(q + (size_t)b * 4096 + (h * kG + g) * kD + d);
        qs[g * kD + d] = qv * (kScale * kLog2e);
    }
    if (tid < kTotP) {
        int pg;
        if (tid < kL0P)             pg = sp0[tid];
        else if (tid < kL0P + kL1P) pg = sp1[b * kL1P + (tid - kL0P)];
        else                        pg = sp2[b * kL2P + (tid - kL0P - kL1P)];
        plist[tid] = pg;
    }
    __syncthreads();

    const int w = tid >> 6;
    const int lane = tid & 63;
    const int ts = lane >> 4;              // page-slot for QK / token-quarter for PV
    const int dg = lane & 15;              // 8-dim group for PV
    const int pbase = w * kPPW;
    const float4* qv4 = (const float4*)qs;

    float m[kG], l[kG], acc[kG][8];
#pragma unroll
    for (int g = 0; g < kG; ++g) {
        m[g] = -1e30f; l[g] = 0.f;
#pragma unroll
        for (int e = 0; e < 8; ++e) acc[g][e] = 0.f;
    }

    for (int tile = 0; tile < kTiles; ++tile) {
        const int page = plist[pbase + tile * 4 + ts];
        const size_t poff = (size_t)page * 32768u;
        // QK: lane = tile-token (page slot ts, token lane&15)
        const T* Kp = kv + poff + (size_t)(lane & 15) * 1024u + h * 128;
        // PV: lane = (token-quarter ts, dim-group dg); same page as its QK slot
        const T* Vp = kv + poff + 16384u + h * 128 + dg * 8;

        float s[kG] = {0.f, 0.f, 0.f, 0.f};
#pragma unroll
        for (int c = 0; c < 16; ++c) {
            float kf[8];
            load8(Kp + c * 8, kf);
#pragma unroll
            for (int g = 0; g < kG; ++g) {
                float4 qa = qv4[g * 32 + c * 2];   // uniform LDS broadcast
                float4 qb = qv4[g * 32 + c * 2 + 1];
                s[g] += kf[0] * qa.x + kf[1] * qa.y + kf[2] * qa.z + kf[3] * qa.w
                      + kf[4] * qb.x + kf[5] * qb.y + kf[6] * qb.z + kf[7] * qb.w;
            }
        }

        // online softmax update (base-2 domain; q carries log2e*scale)
        float p[kG];
#pragma unroll
        for (int g = 0; g < kG; ++g) {
            float mt = wave_max(s[g]);
            float mn = fmaxf(m[g], mt);
            float alpha = exp2f(m[g] - mn);
            p[g] = exp2f(s[g] - mn);
            m[g] = mn;
            l[g] = l[g] * alpha + wave_sum(p[g]);
#pragma unroll
            for (int e = 0; e < 8; ++e) acc[g][e] *= alpha;
        }

        // PV: lane accumulates dims [dg*8, dg*8+8) over its 16-token quarter;
        // p is in lane=token layout, fetched via in-wave shuffle.
#pragma unroll
        for (int j = 0; j < 16; ++j) {
            const int t = ts * 16 + j;
            float vf[8];
            load8(Vp + (size_t)j * 1024u, vf);
            float pj[kG];
#pragma unroll
            for (int g = 0; g < kG; ++g) pj[g] = __shfl(p[g], t);
#pragma unroll
            for (int g = 0; g < kG; ++g)
#pragma unroll
                for (int e = 0; e < 8; ++e)
                    acc[g][e] = fmaf(pj[g], vf[e], acc[g][e]);
        }
    }

    // reduce acc across the 4 token-quarters (lane^16, lane^32)
#pragma unroll
    for (int g = 0; g < kG; ++g)
#pragma unroll
        for (int e = 0; e < 8; ++e) {
            float v = acc[g][e];
            v += __shfl_xor(v, 16);
            v += __shfl_xor(v, 32);
            acc[g][e] = v;
        }
    if (lane < 16) {
#pragma unroll
        for (int g = 0; g < kG; ++g) {
            *(float4*)&wacc[w][g * kD + dg * 8]     = make_float4(acc[g][0], acc[g][1], acc[g][2], acc[g][3]);
            *(float4*)&wacc[w][g * kD + dg * 8 + 4] = make_float4(acc[g][4], acc[g][5], acc[g][6], acc[g][7]);
        }
        if (lane == 0) {
#pragma unroll
            for (int g = 0; g < kG; ++g) { wm[w][g] = m[g]; wl[w][g] = l[g]; }
        }
    }
    __syncthreads();

    // merge the 8 wave states (exact LSE-weighted merge), write out
    {
        const int g = tid >> 7;
        const int d = tid & 127;
        float mstar = wm[0][g];
#pragma unroll
        for (int ww = 1; ww < kWaves; ++ww) mstar = fmaxf(mstar, wm[ww][g]);
        float numer = 0.f, denom = 0.f;
#pragma unroll
        for (int ww = 0; ww < kWaves; ++ww) {
            float sc = exp2f(wm[ww][g] - mstar);
            denom = fmaf(sc, wl[ww][g], denom);
            numer = fmaf(sc, wacc[ww][g * kD + d], numer);
        }
        st1(out + (size_t)b * 4096 + (h * kG + g) * kD + d, numer / denom);
    }
}

__global__ __launch_bounds__(512, 2)
void cascade_attn_kernel(const void* __restrict__ qraw,
                         const void* __restrict__ kvraw,
                         const int* __restrict__ sp0,
                         const int* __restrict__ sp1,
                         const int* __restrict__ sp2,
                         void* __restrict__ outraw)
{
    // --- runtime dtype detection from q's bit patterns ---
    // bf16 data: low 16 bits of each 32b word are a bf16 of N(0,1) -> exponent
    // field ((w>>7)&0xFF) in [0x70,0x85] essentially always.
    // fp32 data: those bits are uniform mantissa junk -> in-range ~8.6%.
    __shared__ int s_isbf;
    if (threadIdx.x == 0) {
        const unsigned* wq = (const unsigned*)qraw;
        int cnt = 0;
#pragma unroll
        for (int i = 0; i < 64; ++i) {
            unsigned e = (wq[i] >> 7) & 0xFFu;
            cnt += (e >= 0x70u && e <= 0x85u) ? 1 : 0;
        }
        s_isbf = (cnt >= 32);
    }
    __syncthreads();

    const int b = blockIdx.x >> 3;
    const int h = blockIdx.x & 7;
    if (s_isbf) {
        run_attn<unsigned short>((const unsigned short*)qraw, (const unsigned short*)kvraw,
                                 sp0, sp1, sp2, (unsigned short*)outraw, b, h, threadIdx.x);
    } else {
        run_attn<float>((const float*)qraw, (const float*)kvraw,
                        sp0, sp1, sp2, (float*)outraw, b, h, threadIdx.x);
    }
}

extern "C" void kernel_launch(void* const* d_in, const int* in_sizes, int n_in,
                              void* d_out, int out_size, void* d_ws, size_t ws_size,
                              hipStream_t stream) {
    hipLaunchKernelGGL(cascade_attn_kernel, dim3(32 * 8), dim3(512), 0, stream,
                       d_in[0], d_in[1], (const int*)d_in[2], (const int*)d_in[3],
                       (const int*)d_in[4], d_out);
}

// Round 3
// 687.148 us; speedup vs baseline: 1.6452x; 1.6452x over previous
//
#include <hip/hip_runtime.h>
#include <stdint.h>

// CascadeAttention decode, MI355X (gfx950). fp32 confirmed (R2 FETCH=1.55GB
// matches fp32 per-block traffic; bf16 would be half that).
//
// 3-kernel cascade:
//  K1 l0_kernel  : 256 blocks (h, chunk of 8 pages). Stages the chunk's K/V
//                  h-slice (128 KB) into LDS (XOR-swizzled), computes partial
//                  attention for ALL 32 b from LDS. Kills the 32x re-fetch of
//                  the shared prefix seen in R2 (1.0 GB -> ~35 MB).
//  K2 seq_kernel : 768 blocks (b, h, split of 32 pages). One 4-page tile per
//                  wave, single-tile softmax, block-level LSE merge -> partial.
//                  3x R2's occupancy to fix the 32%-of-peak latency bind.
//  K3 merge      : 256 blocks; exact LSE merge of 35 partials per (b,h,g).
// ws = 35 srcs x [32 b][8 h][4 g][128 d] fp32 + m/l pairs = 18.6 MB.
// Host falls back to the proven R2 single-kernel if ws_size is too small.

namespace {
constexpr int kG = 4, kD = 128;
constexpr float kQS = 0.08838834764831845f * 1.4426950408889634f; // scale*log2e
constexpr int kNChunk = 32;   // L0: 32 chunks x 8 pages
constexpr int kNSplit = 3;    // seq: 3 splits x 32 pages
constexpr int kNSrc = kNChunk + kNSplit;              // 35
constexpr size_t kOParts = (size_t)kNSrc * 32 * 8 * 4 * 128;   // o floats
constexpr size_t kMLB = kOParts;                               // m/l base
constexpr size_t kWsFloats = kOParts + (size_t)kNSrc * 32 * 8 * 4 * 2;
// kv strides (floats): page 32768, K->V 16384, token 1024, kvh 128
}

__device__ __forceinline__ float wave_max(float v) {
#pragma unroll
    for (int off = 1; off < 64; off <<= 1) v = fmaxf(v, __shfl_xor(v, off));
    return v;
}
__device__ __forceinline__ float wave_sum(float v) {
#pragma unroll
    for (int off = 1; off < 64; off <<= 1) v += __shfl_xor(v, off);
    return v;
}
// 16B-slot swizzles (32 slots per 128-float row) for conflict-free LDS.
__device__ __forceinline__ int kslot(int s, int t) { return s ^ (t & 31); }
__device__ __forceinline__ int vslot(int s, int t) {
    return s ^ (((t << 1) & 31) | ((t >> 4) & 1));
}

// ---------------- K1: shared-prefix, K-stationary in LDS -------------------
__global__ __launch_bounds__(512, 2)
void l0_kernel(const float* __restrict__ q, const float* __restrict__ kv,
               const int* __restrict__ sp0, float* __restrict__ ws)
{
    __shared__ __align__(16) float q_lds[32 * kG * kD];   // 64 KB, [b][g][d]
    __shared__ __align__(16) float buf[2 * 64 * kD];      // 64 KB: K then V
    __shared__ int pgs[8];

    const int h = blockIdx.x & 7;
    const int chunk = blockIdx.x >> 3;
    const int tid = threadIdx.x;
    const int w = tid >> 6, lane = tid & 63;

    // stage q for all 32 b (this h), pre-scaled: 16384 floats, 32 per thread
    {
        const int j0 = tid * 32;
        const int b = j0 >> 9, r = j0 & 511;
        const float4* src = (const float4*)(q + (size_t)b * 4096 + h * 512 + r);
        float4* dst = (float4*)&q_lds[j0];
#pragma unroll
        for (int u = 0; u < 8; ++u) {
            float4 v = src[u];
            v.x *= kQS; v.y *= kQS; v.z *= kQS; v.w *= kQS;
            dst[u] = v;
        }
    }
    if (tid < 8) pgs[tid] = sp0[chunk * 8 + tid];

    // two b-passes (2 b per wave per pass) keep VGPRs ~150 (no spill risk)
    for (int pass = 0; pass < 2; ++pass) {
        float m[8], l[8], acc[8][8];
#pragma unroll
        for (int r = 0; r < 8; ++r) {
            m[r] = -1e30f; l[r] = 0.f;
#pragma unroll
            for (int e = 0; e < 8; ++e) acc[r][e] = 0.f;
        }

        for (int st = 0; st < 2; ++st) {           // 2 stages x 4 pages
            __syncthreads();                        // prev compute done
            {   // stage 64 tokens of K and V, swizzled
                const int t = tid >> 3;             // 0..63
                const int sg = (tid & 7) * 4;       // 4 slots = 64 B
                const int pg = pgs[st * 4 + (t >> 4)];
                const float* gk = kv + (size_t)pg * 32768 + (size_t)(t & 15) * 1024 + h * 128;
#pragma unroll
                for (int j = 0; j < 4; ++j) {
                    const int s = sg + j;
                    *(float4*)&buf[t * 128 + (kslot(s, t) << 2)] =
                        *(const float4*)(gk + s * 4);
                    *(float4*)&buf[8192 + t * 128 + (vslot(s, t) << 2)] =
                        *(const float4*)(gk + 16384 + s * 4);
                }
            }
            __syncthreads();

            // ---- compute: 8 rows = 2 b x 4 g; lane = token ----
            const int sw = lane;
            float s[8] = {0.f,0.f,0.f,0.f,0.f,0.f,0.f,0.f};
#pragma unroll
            for (int c = 0; c < 16; ++c) {
                float4 ka = *(const float4*)&buf[lane * 128 + (kslot(2 * c, sw) << 2)];
                float4 kb = *(const float4*)&buf[lane * 128 + (kslot(2 * c + 1, sw) << 2)];
#pragma unroll
                for (int r = 0; r < 8; ++r) {
                    const int b = w * 4 + pass * 2 + (r >> 2);
                    const float* qp = &q_lds[(b * 4 + (r & 3)) * 128 + c * 8];
                    float4 qa = *(const float4*)qp;
                    float4 qb = *(const float4*)(qp + 4);
                    s[r] += ka.x * qa.x + ka.y * qa.y + ka.z * qa.z + ka.w * qa.w
                          + kb.x * qb.x + kb.y * qb.y + kb.z * qb.z + kb.w * qb.w;
                }
            }
            float p[8];
#pragma unroll
            for (int r = 0; r < 8; ++r) {
                float mt = wave_max(s[r]);
                float mn = fmaxf(m[r], mt);
                float alpha = exp2f(m[r] - mn);
                p[r] = exp2f(s[r] - mn);
                m[r] = mn;
                l[r] = l[r] * alpha + wave_sum(p[r]);
#pragma unroll
                for (int e = 0; e < 8; ++e) acc[r][e] *= alpha;
            }
            const int tq = lane >> 4, dg = lane & 15;
#pragma unroll
            for (int j = 0; j < 16; ++j) {
                const int t = tq * 16 + j;
                float4 va = *(const float4*)&buf[8192 + t * 128 + (vslot(2 * dg, t) << 2)];
                float4 vb = *(const float4*)&buf[8192 + t * 128 + (vslot(2 * dg + 1, t) << 2)];
#pragma unroll
                for (int r = 0; r < 8; ++r) {
                    float pj = __shfl(p[r], t);
                    acc[r][0] = fmaf(pj, va.x, acc[r][0]);
                    acc[r][1] = fmaf(pj, va.y, acc[r][1]);
                    acc[r][2] = fmaf(pj, va.z, acc[r][2]);
                    acc[r][3] = fmaf(pj, va.w, acc[r][3]);
                    acc[r][4] = fmaf(pj, vb.x, acc[r][4]);
                    acc[r][5] = fmaf(pj, vb.y, acc[r][5]);
                    acc[r][6] = fmaf(pj, vb.z, acc[r][6]);
                    acc[r][7] = fmaf(pj, vb.w, acc[r][7]);
                }
            }
        }

        // reduce over the 4 token-quarters; write partial (o unnormalized, m, l)
#pragma unroll
        for (int r = 0; r < 8; ++r)
#pragma unroll
            for (int e = 0; e < 8; ++e) {
                float v = acc[r][e];
                v += __shfl_xor(v, 16);
                v += __shfl_xor(v, 32);
                acc[r][e] = v;
            }
        if (lane < 16) {
            const int dg = lane;
#pragma unroll
            for (int r = 0; r < 8; ++r) {
                const int b = w * 4 + pass * 2 + (r >> 2);
                const size_t ob = ((((size_t)chunk * 32 + b) * 8 + h) * 4 + (r & 3)) * 128 + dg * 8;
                *(float4*)&ws[ob]     = make_float4(acc[r][0], acc[r][1], acc[r][2], acc[r][3]);
                *(float4*)&ws[ob + 4] = make_float4(acc[r][4], acc[r][5], acc[r][6], acc[r][7]);
            }
        }
        if (lane == 0) {
#pragma unroll
            for (int r = 0; r < 8; ++r) {
                const int b = w * 4 + pass * 2 + (r >> 2);
                const size_t idx = (((size_t)chunk * 32 + b) * 8 + h) * 4 + (r & 3);
                ws[kMLB + 2 * idx] = m[r];
                ws[kMLB + 2 * idx + 1] = l[r];
            }
        }
    }
}

// ---------------- K2: per-sequence levels, split 3x ------------------------
__global__ __launch_bounds__(512, 4)
void seq_kernel(const float* __restrict__ q, const float* __restrict__ kv,
                const int* __restrict__ sp1, const int* __restrict__ sp2,
                float* __restrict__ ws)
{
    __shared__ __align__(16) float qs[kG * kD];
    __shared__ int plist[32];
    __shared__ __align__(16) float wacc[8][kG * kD];
    __shared__ float wm[8][kG], wl[8][kG];

    const int bid = blockIdx.x;
    const int split = bid >> 8;
    const int b = (bid & 255) >> 3;
    const int h = bid & 7;
    const int tid = threadIdx.x;

    {
        const int g = tid >> 7, d = tid & 127;
        qs[g * 128 + d] = q[(size_t)b * 4096 + h * 512 + g * 128 + d] * kQS;
    }
    if (tid < 32) {
        const int gi = split * 32 + tid;
        plist[tid] = (gi < 64) ? sp1[b * 64 + gi] : sp2[b * 32 + (gi - 64)];
    }
    __syncthreads();

    const int w = tid >> 6, lane = tid & 63;
    const int ts = lane >> 4, dg = lane & 15;
    const int page = plist[w * 4 + ts];
    const size_t poff = (size_t)page * 32768u;
    const float* Kp = kv + poff + (size_t)(lane & 15) * 1024u + h * 128;
    const float* Vp = kv + poff + 16384u + h * 128 + dg * 8;
    const float4* qv4 = (const float4*)qs;

    // single 64-token tile per wave
    float s[kG] = {0.f, 0.f, 0.f, 0.f};
#pragma unroll
    for (int c = 0; c < 16; ++c) {
        float4 ka = *(const float4*)(Kp + c * 8);
        float4 kb = *(const float4*)(Kp + c * 8 + 4);
#pragma unroll
        for (int g = 0; g < kG; ++g) {
            float4 qa = qv4[g * 32 + c * 2];
            float4 qb = qv4[g * 32 + c * 2 + 1];
            s[g] += ka.x * qa.x + ka.y * qa.y + ka.z * qa.z + ka.w * qa.w
                  + kb.x * qb.x + kb.y * qb.y + kb.z * qb.z + kb.w * qb.w;
        }
    }
    float m[kG], p[kG], l[kG], acc[kG][8];
#pragma unroll
    for (int g = 0; g < kG; ++g) {
        m[g] = wave_max(s[g]);
        p[g] = exp2f(s[g] - m[g]);
        l[g] = wave_sum(p[g]);
#pragma unroll
        for (int e = 0; e < 8; ++e) acc[g][e] = 0.f;
    }
#pragma unroll
    for (int j = 0; j < 16; ++j) {
        const int t = ts * 16 + j;
        float4 va = *(const float4*)(Vp + (size_t)j * 1024u);
        float4 vb = *(const float4*)(Vp + (size_t)j * 1024u + 4);
#pragma unroll
        for (int g = 0; g < kG; ++g) {
            float pj = __shfl(p[g], t);
            acc[g][0] = fmaf(pj, va.x, acc[g][0]);
            acc[g][1] = fmaf(pj, va.y, acc[g][1]);
            acc[g][2] = fmaf(pj, va.z, acc[g][2]);
            acc[g][3] = fmaf(pj, va.w, acc[g][3]);
            acc[g][4] = fmaf(pj, vb.x, acc[g][4]);
            acc[g][5] = fmaf(pj, vb.y, acc[g][5]);
            acc[g][6] = fmaf(pj, vb.z, acc[g][6]);
            acc[g][7] = fmaf(pj, vb.w, acc[g][7]);
        }
    }
#pragma unroll
    for (int g = 0; g < kG; ++g)
#pragma unroll
        for (int e = 0; e < 8; ++e) {
            float v = acc[g][e];
            v += __shfl_xor(v, 16);
            v += __shfl_xor(v, 32);
            acc[g][e] = v;
        }
    if (lane < 16) {
#pragma unroll
        for (int g = 0; g < kG; ++g) {
            *(float4*)&wacc[w][g * 128 + dg * 8]     = make_float4(acc[g][0], acc[g][1], acc[g][2], acc[g][3]);
            *(float4*)&wacc[w][g * 128 + dg * 8 + 4] = make_float4(acc[g][4], acc[g][5], acc[g][6], acc[g][7]);
        }
        if (lane == 0)
#pragma unroll
            for (int g = 0; g < kG; ++g) { wm[w][g] = m[g]; wl[w][g] = l[g]; }
    }
    __syncthreads();

    {   // block-level merge of the 8 wave states -> one partial to ws
        const int g = tid >> 7, d = tid & 127;
        float mstar = wm[0][g];
#pragma unroll
        for (int ww = 1; ww < 8; ++ww) mstar = fmaxf(mstar, wm[ww][g]);
        float numer = 0.f, denom = 0.f;
#pragma unroll
        for (int ww = 0; ww < 8; ++ww) {
            float sc = exp2f(wm[ww][g] - mstar);
            denom = fmaf(sc, wl[ww][g], denom);
            numer = fmaf(sc, wacc[ww][g * 128 + d], numer);
        }
        const size_t src = (size_t)(kNChunk + split);
        const size_t ob = (((src * 32 + b) * 8 + h) * 4 + g) * 128 + d;
        ws[ob] = numer;
        if (d == 0) {
            const size_t idx = ((src * 32 + b) * 8 + h) * 4 + g;
            ws[kMLB + 2 * idx] = mstar;
            ws[kMLB + 2 * idx + 1] = denom;
        }
    }
}

// ---------------- K3: final merge of 35 partials ---------------------------
__global__ __launch_bounds__(512, 4)
void merge_kernel(const float* __restrict__ ws, float* __restrict__ out)
{
    __shared__ float sm[kNSrc][4], sl[kNSrc][4];
    const int b = blockIdx.x >> 3, h = blockIdx.x & 7;
    const int tid = threadIdx.x;
    if (tid < kNSrc * 4) {
        const int src = tid >> 2, g = tid & 3;
        const size_t idx = ((((size_t)src * 32 + b) * 8 + h) * 4 + g);
        sm[src][g] = ws[kMLB + 2 * idx];
        sl[src][g] = ws[kMLB + 2 * idx + 1];
    }
    __syncthreads();
    const int g = tid >> 7, d = tid & 127;
    float mstar = -1e30f;
#pragma unroll
    for (int s = 0; s < kNSrc; ++s) mstar = fmaxf(mstar, sm[s][g]);
    float numer = 0.f, denom = 0.f;
#pragma unroll 7
    for (int s = 0; s < kNSrc; ++s) {
        const float sc = exp2f(sm[s][g] - mstar);
        denom = fmaf(sc, sl[s][g], denom);
        const size_t ob = ((((size_t)s * 32 + b) * 8 + h) * 4 + g) * 128 + d;
        numer = fmaf(sc, ws[ob], numer);
    }
    out[(size_t)b * 4096 + h * 512 + g * 128 + d] = numer / denom;
}

// ---------------- fallback: proven R2 single kernel (fp32) -----------------
__global__ __launch_bounds__(512, 2)
void fallback_kernel(const float* __restrict__ q, const float* __restrict__ kv,
                     const int* __restrict__ sp0, const int* __restrict__ sp1,
                     const int* __restrict__ sp2, float* __restrict__ out)
{
    __shared__ __align__(16) float qs[kG * kD];
    __shared__ int plist[352];
    __shared__ __align__(16) float wacc[8][kG * kD];
    __shared__ float wm[8][kG], wl[8][kG];
    const int b = blockIdx.x >> 3, h = blockIdx.x & 7;
    const int tid = threadIdx.x;
    {
        const int g = tid >> 7, d = tid & 127;
        qs[g * 128 + d] = q[(size_t)b * 4096 + h * 512 + g * 128 + d] * kQS;
    }
    if (tid < 352) {
        int pg;
        if (tid < 256)      pg = sp0[tid];
        else if (tid < 320) pg = sp1[b * 64 + (tid - 256)];
        else                pg = sp2[b * 32 + (tid - 320)];
        plist[tid] = pg;
    }
    __syncthreads();
    const int w = tid >> 6, lane = tid & 63;
    const int ts = lane >> 4, dg = lane & 15;
    const float4* qv4 = (const float4*)qs;
    float m[kG], l[kG], acc[kG][8];
#pragma unroll
    for (int g = 0; g < kG; ++g) {
        m[g] = -1e30f; l[g] = 0.f;
#pragma unroll
        for (int e = 0; e < 8; ++e) acc[g][e] = 0.f;
    }
    for (int tile = 0; tile < 11; ++tile) {
        const int page = plist[w * 44 + tile * 4 + ts];
        const size_t poff = (size_t)page * 32768u;
        const float* Kp = kv + poff + (size_t)(lane & 15) * 1024u + h * 128;
        const float* Vp = kv + poff + 16384u + h * 128 + dg * 8;
        float s[kG] = {0.f, 0.f, 0.f, 0.f};
#pragma unroll
        for (int c = 0; c < 16; ++c) {
            float4 ka = *(const float4*)(Kp + c * 8);
            float4 kb = *(const float4*)(Kp + c * 8 + 4);
#pragma unroll
            for (int g = 0; g < kG; ++g) {
                float4 qa = qv4[g * 32 + c * 2];
                float4 qb = qv4[g * 32 + c * 2 + 1];
                s[g] += ka.x * qa.x + ka.y * qa.y + ka.z * qa.z + ka.w * qa.w
                      + kb.x * qb.x + kb.y * qb.y + kb.z * qb.z + kb.w * qb.w;
            }
        }
        float p[kG];
#pragma unroll
        for (int g = 0; g < kG; ++g) {
            float mt = wave_max(s[g]);
            float mn = fmaxf(m[g], mt);
            float alpha = exp2f(m[g] - mn);
            p[g] = exp2f(s[g] - mn);
            m[g] = mn;
            l[g] = l[g] * alpha + wave_sum(p[g]);
#pragma unroll
            for (int e = 0; e < 8; ++e) acc[g][e] *= alpha;
        }
#pragma unroll
        for (int j = 0; j < 16; ++j) {
            const int t = ts * 16 + j;
            float4 va = *(const float4*)(Vp + (size_t)j * 1024u);
            float4 vb = *(const float4*)(Vp + (size_t)j * 1024u + 4);
#pragma unroll
            for (int g = 0; g < kG; ++g) {
                float pj = __shfl(p[g], t);
                acc[g][0] = fmaf(pj, va.x, acc[g][0]);
                acc[g][1] = fmaf(pj, va.y, acc[g][1]);
                acc[g][2] = fmaf(pj, va.z, acc[g][2]);
                acc[g][3] = fmaf(pj, va.w, acc[g][3]);
                acc[g][4] = fmaf(pj, vb.x, acc[g][4]);
                acc[g][5] = fmaf(pj, vb.y, acc[g][5]);
                acc[g][6] = fmaf(pj, vb.z, acc[g][6]);
                acc[g][7] = fmaf(pj, vb.w, acc[g][7]);
            }
        }
    }
#pragma unroll
    for (int g = 0; g < kG; ++g)
#pragma unroll
        for (int e = 0; e < 8; ++e) {
            float v = acc[g][e];
            v += __shfl_xor(v, 16);
            v += __shfl_xor(v, 32);
            acc[g][e] = v;
        }
    if (lane < 16) {
#pragma unroll
        for (int g = 0; g < kG; ++g) {
            *(float4*)&wacc[w][g * 128 + dg * 8]     = make_float4(acc[g][0], acc[g][1], acc[g][2], acc[g][3]);
            *(float4*)&wacc[w][g * 128 + dg * 8 + 4] = make_float4(acc[g][4], acc[g][5], acc[g][6], acc[g][7]);
        }
        if (lane == 0)
#pragma unroll
            for (int g = 0; g < kG; ++g) { wm[w][g] = m[g]; wl[w][g] = l[g]; }
    }
    __syncthreads();
    {
        const int g = tid >> 7, d = tid & 127;
        float mstar = wm[0][g];
#pragma unroll
        for (int ww = 1; ww < 8; ++ww) mstar = fmaxf(mstar, wm[ww][g]);
        float numer = 0.f, denom = 0.f;
#pragma unroll
        for (int ww = 0; ww < 8; ++ww) {
            float sc = exp2f(wm[ww][g] - mstar);
            denom = fmaf(sc, wl[ww][g], denom);
            numer = fmaf(sc, wacc[ww][g * 128 + d], numer);
        }
        out[(size_t)b * 4096 + h * 512 + g * 128 + d] = numer / denom;
    }
}

extern "C" void kernel_launch(void* const* d_in, const int* in_sizes, int n_in,
                              void* d_out, int out_size, void* d_ws, size_t ws_size,
                              hipStream_t stream) {
    const float* q  = (const float*)d_in[0];
    const float* kv = (const float*)d_in[1];
    const int* sp0 = (const int*)d_in[2];
    const int* sp1 = (const int*)d_in[3];
    const int* sp2 = (const int*)d_in[4];
    float* out = (float*)d_out;
    float* ws = (float*)d_ws;
    if (ws_size >= kWsFloats * sizeof(float)) {
        hipLaunchKernelGGL(l0_kernel,    dim3(256), dim3(512), 0, stream, q, kv, sp0, ws);
        hipLaunchKernelGGL(seq_kernel,   dim3(768), dim3(512), 0, stream, q, kv, sp1, sp2, ws);
        hipLaunchKernelGGL(merge_kernel, dim3(256), dim3(512), 0, stream, ws, out);
    } else {
        hipLaunchKernelGGL(fallback_kernel, dim3(256), dim3(512), 0, stream,
                           q, kv, sp0, sp1, sp2, out);
    }
}